// Round 6
// baseline (1166.148 us; speedup 1.0000x reference)
//
#include <hip/hip_runtime.h>
#include <cstdint>

#define B 1024
#define D 1024
#define S 64
#define ND 4
#define HD 64
#define F 4096
#define NSTEPS 4

typedef __attribute__((ext_vector_type(8))) short short8v;
typedef __attribute__((ext_vector_type(4))) float f32x4;

// ---------------- helpers ----------------
__device__ __forceinline__ float wsum(float v) {
#pragma unroll
  for (int o = 32; o; o >>= 1) v += __shfl_xor(v, o);
  return v;
}
__device__ __forceinline__ float wmax(float v) {
#pragma unroll
  for (int o = 32; o; o >>= 1) v = fmaxf(v, __shfl_xor(v, o));
  return v;
}
__device__ __forceinline__ float gelu_tanh(float x) {
  const float c = 0.79788456080286535588f;  // sqrt(2/pi)
  float x3 = x * x * x;
  return 0.5f * x * (1.f + tanhf(c * (x + 0.044715f * x3)));
}
__device__ __forceinline__ ushort f2bf(float f) {
  uint32_t u = __float_as_uint(f);
  u += 0x7fffu + ((u >> 16) & 1u);
  return (ushort)(u >> 16);
}
__device__ __forceinline__ float bf2f(ushort u) {
  return __uint_as_float(((uint32_t)u) << 16);
}
__device__ __forceinline__ void gload16(const void* g, void* l) {
  __builtin_amdgcn_global_load_lds(
      (const __attribute__((address_space(1))) void*)g,
      (__attribute__((address_space(3))) void*)l, 16, 0, 0);
}

// ---------------- fp32 -> bf16 convert ----------------
__global__ __launch_bounds__(256) void cvt_bf16_kernel(
    const float* __restrict__ in, ushort* __restrict__ out, int n4) {
  const int idx = blockIdx.x * 256 + threadIdx.x;
  if (idx < n4) {
    const float4 v = ((const float4*)in)[idx];
    ushort4 o;
    o.x = f2bf(v.x); o.y = f2bf(v.y); o.z = f2bf(v.z); o.w = f2bf(v.w);
    ((ushort4*)out)[idx] = o;
  }
}

// ---------------- fp32 [R][C] -> bf16 [C][R] transpose ----------------
__global__ __launch_bounds__(256) void transpose_bf16_kernel(
    const float* __restrict__ in, ushort* __restrict__ out, int R, int C) {
  __shared__ float ld[32][33];
  const int tid = threadIdx.x;
  const int r0 = blockIdx.y << 5, c0 = blockIdx.x << 5;
  const int ty = tid >> 3, tx4 = (tid & 7) << 2;
  const float4 v = *(const float4*)(in + (size_t)(r0 + ty) * C + c0 + tx4);
  ld[ty][tx4 + 0] = v.x;
  ld[ty][tx4 + 1] = v.y;
  ld[ty][tx4 + 2] = v.z;
  ld[ty][tx4 + 3] = v.w;
  __syncthreads();
  ushort4 o;
  o.x = f2bf(ld[tx4 + 0][ty]);
  o.y = f2bf(ld[tx4 + 1][ty]);
  o.z = f2bf(ld[tx4 + 2][ty]);
  o.w = f2bf(ld[tx4 + 3][ty]);
  *(ushort4*)(out + (size_t)(c0 + ty) * R + r0 + tx4) = o;
}

// ---------------- bf16 MFMA GEMM ----------------
// C[M=1024, N] = A[M,K]@B  with B given as Bt[N][K] (bf16, row stride ldb).
// PARTIAL: write raw fp32 to Cv + kz*1024*N (split-K partials, no epilogue).
// else: v = acc (+bias[n]); if ACT gelu; store bf16 or fp32.
template <bool PARTIAL, bool BF16OUT, bool ACT>
__global__ __launch_bounds__(256) void gemm_mfma(
    const ushort* __restrict__ A, int lda, const ushort* __restrict__ Bt,
    int ldb, const float* __restrict__ bias, void* __restrict__ Cv, int N,
    int KCHUNK) {
  __shared__ ushort As[128 * 32];
  __shared__ ushort Bs[128 * 32];
  const int tid = threadIdx.x;
  const int w = tid >> 6, l = tid & 63;
  const int m0 = blockIdx.y << 7;
  const int n0 = blockIdx.x << 7;
  const int kz = blockIdx.z;

  const ushort* Ab = A + (size_t)m0 * lda + (size_t)kz * KCHUNK;
  const ushort* Bb = Bt + (size_t)n0 * ldb + (size_t)kz * KCHUNK;

  f32x4 acc[4][4];
#pragma unroll
  for (int i = 0; i < 4; ++i)
#pragma unroll
    for (int j = 0; j < 4; ++j) acc[i][j] = (f32x4){0.f, 0.f, 0.f, 0.f};

  const int srow = tid >> 2;            // 0..63
  const int schunk = (tid & 3) << 3;    // k elem offset 0/8/16/24
  ushort* AsW = As + (w << 9);          // wave-uniform LDS base
  ushort* BsW = Bs + (w << 9);

  const int ar = ((w >> 1) << 6) + (l & 15);
  const int br = ((w & 1) << 6) + (l & 15);
  const int kofs = (l >> 4) << 3;

  for (int k0 = 0; k0 < KCHUNK; k0 += 32) {
    __syncthreads();
    gload16(Ab + (size_t)srow * lda + k0 + schunk, AsW);
    gload16(Ab + (size_t)(srow + 64) * lda + k0 + schunk, AsW + 2048);
    gload16(Bb + (size_t)srow * ldb + k0 + schunk, BsW);
    gload16(Bb + (size_t)(srow + 64) * ldb + k0 + schunk, BsW + 2048);
    asm volatile("s_waitcnt vmcnt(0)" ::: "memory");
    __syncthreads();

    short8v af[4], bfr[4];
#pragma unroll
    for (int mi = 0; mi < 4; ++mi)
      af[mi] = *(const short8v*)&As[(ar + mi * 16) * 32 + kofs];
#pragma unroll
    for (int ni = 0; ni < 4; ++ni)
      bfr[ni] = *(const short8v*)&Bs[(br + ni * 16) * 32 + kofs];
#pragma unroll
    for (int mi = 0; mi < 4; ++mi)
#pragma unroll
      for (int ni = 0; ni < 4; ++ni)
        acc[mi][ni] = __builtin_amdgcn_mfma_f32_16x16x32_bf16(
            af[mi], bfr[ni], acc[mi][ni], 0, 0, 0);
  }

  const int orow = m0 + ((w >> 1) << 6) + ((l >> 4) << 2);
  const int ocol = n0 + ((w & 1) << 6) + (l & 15);

  if (PARTIAL) {
    float* P = (float*)Cv + (size_t)kz * 1024 * N;
#pragma unroll
    for (int mi = 0; mi < 4; ++mi)
#pragma unroll
      for (int r = 0; r < 4; ++r) {
        const int row = orow + mi * 16 + r;
#pragma unroll
        for (int ni = 0; ni < 4; ++ni)
          P[(size_t)row * N + ocol + ni * 16] = acc[mi][ni][r];
      }
  } else {
    float bv[4];
#pragma unroll
    for (int ni = 0; ni < 4; ++ni) bv[ni] = bias ? bias[ocol + ni * 16] : 0.f;
#pragma unroll
    for (int mi = 0; mi < 4; ++mi)
#pragma unroll
      for (int r = 0; r < 4; ++r) {
        const int row = orow + mi * 16 + r;
#pragma unroll
        for (int ni = 0; ni < 4; ++ni) {
          float v = acc[mi][ni][r] + bv[ni];
          if (ACT) v = gelu_tanh(v);
          if (BF16OUT)
            ((ushort*)Cv)[(size_t)row * N + ocol + ni * 16] = f2bf(v);
          else
            ((float*)Cv)[(size_t)row * N + ocol + ni * 16] = v;
        }
      }
  }
}

// ---------------- split-K reduce: out = sum_z part + bias + resid ----------
__global__ __launch_bounds__(256) void reduce4_kernel(
    const float* __restrict__ part, const float* __restrict__ bias,
    const float* __restrict__ resid, float* __restrict__ out) {
  const int idx = blockIdx.x * 256 + threadIdx.x;  // float4 idx, 256K total
  const float4* p = (const float4*)part;
  float4 v = p[idx];
  const float4 v1 = p[idx + 262144];
  const float4 v2 = p[idx + 2 * 262144];
  const float4 v3 = p[idx + 3 * 262144];
  v.x += v1.x + v2.x + v3.x;
  v.y += v1.y + v2.y + v3.y;
  v.z += v1.z + v2.z + v3.z;
  v.w += v1.w + v2.w + v3.w;
  if (bias) {
    const float4 bb = ((const float4*)bias)[idx & 255];
    v.x += bb.x; v.y += bb.y; v.z += bb.z; v.w += bb.w;
  }
  if (resid) {
    const float4 r = ((const float4*)resid)[idx];
    v.x += r.x; v.y += r.y; v.z += r.z; v.w += r.w;
  }
  ((float4*)out)[idx] = v;
}

// ---------------- write step ----------------
__global__ __launch_bounds__(256) void write_step_kernel(
    const float* __restrict__ x, const float* __restrict__ xk,
    const float* __restrict__ conv_in, float* __restrict__ conv_out,
    ushort* __restrict__ cbf) {
  const int b = blockIdx.x;
  const int tid = threadIdx.x;
  const int wave = tid >> 6, lane = tid & 63;
  __shared__ float xls[D];
  __shared__ float xkls[D];
  __shared__ float wls[S];

  *(float4*)&xls[tid * 4] = ((const float4*)(x + (int64_t)b * D))[tid];
  *(float4*)&xkls[tid * 4] = ((const float4*)(xk + (int64_t)b * D))[tid];
  __syncthreads();

  const float4* xk4 = (const float4*)xkls;
  for (int si = 0; si < 16; ++si) {
    const int s = wave * 16 + si;
    const float4* cp = (const float4*)(conv_in + ((int64_t)b * S + s) * D);
    float4 a = {0.f, 0.f, 0.f, 0.f};
#pragma unroll
    for (int i = 0; i < 4; ++i) {
      const float4 cv = cp[lane + i * 64];
      const float4 qv = xk4[lane + i * 64];
      a.x = fmaf(qv.x, cv.x, a.x);
      a.y = fmaf(qv.y, cv.y, a.y);
      a.z = fmaf(qv.z, cv.z, a.z);
      a.w = fmaf(qv.w, cv.w, a.w);
    }
    float acc = (a.x + a.y) + (a.z + a.w);
    acc = wsum(acc);
    if (lane == 0) wls[s] = acc * 0.03125f;
  }
  __syncthreads();
  if (wave == 0) {
    float v = wls[lane];
    float m = wmax(v);
    float e = __expf(v - m);
    float ssum = wsum(e);
    wls[lane] = e / ssum;
  }
  __syncthreads();

  const float4* cin4 = (const float4*)(conv_in + (int64_t)b * S * D);
  float4* cout4 = (float4*)(conv_out + (int64_t)b * S * D);
  ushort4* cb4 = cbf ? (ushort4*)(cbf + (int64_t)b * S * D) : nullptr;
  const float4* xl4 = (const float4*)xls;
  for (int i = 0; i < 64; ++i) {
    const int idx = tid + (i << 8);
    const int s = idx >> 8;
    const float w = wls[s] * 0.1f;
    const float4 c = cin4[idx];
    const float4 xv = xl4[idx & 255];
    float4 o;
    o.x = 0.9f * c.x + w * xv.x;
    o.y = 0.9f * c.y + w * xv.y;
    o.z = 0.9f * c.z + w * xv.z;
    o.w = 0.9f * c.w + w * xv.w;
    cout4[idx] = o;
    if (cb4) {
      ushort4 ob;
      ob.x = f2bf(o.x); ob.y = f2bf(o.y); ob.z = f2bf(o.z); ob.w = f2bf(o.w);
      cb4[idx] = ob;
    }
  }
}

// ---------------- per-domain attention read ----------------
__global__ __launch_bounds__(64) void domain_read_kernel(
    const float* __restrict__ x, const float* __restrict__ Wdk,
    const float* __restrict__ dst, ushort* __restrict__ rbuf) {
  const int n = blockIdx.x >> 10;
  const int b = blockIdx.x & 1023;
  const int lane = threadIdx.x;
  __shared__ float qls[HD];
  __shared__ float qkls[HD];
  __shared__ float wls_[S];
  __shared__ float st[64][65];

  qls[lane] = x[(int64_t)b * D + n * HD + lane];
  const float4* sp4 = (const float4*)(dst + (int64_t)(n * B + b) * 64 * HD);
#pragma unroll
  for (int i = 0; i < 16; ++i) {
    const int idx = lane + i * 64;
    const int s = idx >> 4;
    const int h4 = (idx & 15) << 2;
    const float4 v = sp4[idx];
    st[s][h4 + 0] = v.x;
    st[s][h4 + 1] = v.y;
    st[s][h4 + 2] = v.z;
    st[s][h4 + 3] = v.w;
  }
  __syncthreads();

  float acc = 0.f;
  const float* wp = Wdk + n * HD * HD;
#pragma unroll 8
  for (int i = 0; i < HD; ++i) acc = fmaf(qls[i], wp[i * HD + lane], acc);
  qkls[lane] = acc;
  __syncthreads();

  float lg = 0.f;
#pragma unroll 8
  for (int h = 0; h < HD; ++h) lg = fmaf(qkls[h], st[lane][h], lg);
  lg *= 0.125f;
  float m = wmax(lg);
  float e = __expf(lg - m);
  float ssum = wsum(e);
  wls_[lane] = e / ssum;
  __syncthreads();

  float r = 0.f;
#pragma unroll 8
  for (int s2 = 0; s2 < 64; ++s2) r = fmaf(wls_[s2], st[s2][lane], r);
  rbuf[(int64_t)b * (ND * HD) + n * HD + lane] = f2bf(r);
}

// ---------------- online-softmax attention over conv slots (+extra) -------
// ctx output is bf16 (feeds next GEMM's A operand).
template <bool CBF>
__global__ __launch_bounds__(256) void attn2_kernel(
    const float* __restrict__ q, const void* __restrict__ convp,
    const float* __restrict__ extra, ushort* __restrict__ ctxb) {
  const int b = blockIdx.x;
  const int tid = threadIdx.x;
  const int w = tid >> 6, l = tid & 63;
  __shared__ float qls[D];
  __shared__ float accs[4][D];
  __shared__ float mws[4], lws[4];

  ((float4*)qls)[tid] = ((const float4*)(q + (size_t)b * D))[tid];
  __syncthreads();

  // hoist q fragments (per-lane dims)
  float qv[16];
  if (CBF) {
#pragma unroll
    for (int i = 0; i < 2; ++i)
#pragma unroll
      for (int j = 0; j < 8; ++j) qv[i * 8 + j] = qls[(l + i * 64) * 8 + j];
  } else {
#pragma unroll
    for (int i = 0; i < 4; ++i)
#pragma unroll
      for (int j = 0; j < 4; ++j) qv[i * 4 + j] = qls[(l + i * 64) * 4 + j];
  }

  float m = -1e30f, lsum = 0.f;
  float acc[16];
#pragma unroll
  for (int i = 0; i < 16; ++i) acc[i] = 0.f;

  for (int si = 0; si < 16; ++si) {
    const int s = w * 16 + si;
    float cv[16];
    float dot = 0.f;
    if (CBF) {
      const ushort* cp = (const ushort*)convp + ((size_t)b * S + s) * D;
#pragma unroll
      for (int i = 0; i < 2; ++i) {
        const short8v vv = ((const short8v*)cp)[l + i * 64];
#pragma unroll
        for (int j = 0; j < 8; ++j) {
          const float c = bf2f((ushort)vv[j]);
          cv[i * 8 + j] = c;
          dot = fmaf(c, qv[i * 8 + j], dot);
        }
      }
    } else {
      const float* cp = (const float*)convp + ((size_t)b * S + s) * D;
#pragma unroll
      for (int i = 0; i < 4; ++i) {
        const float4 vv = ((const float4*)cp)[l + i * 64];
        cv[i * 4 + 0] = vv.x; cv[i * 4 + 1] = vv.y;
        cv[i * 4 + 2] = vv.z; cv[i * 4 + 3] = vv.w;
        dot = fmaf(vv.x, qv[i * 4 + 0], dot);
        dot = fmaf(vv.y, qv[i * 4 + 1], dot);
        dot = fmaf(vv.z, qv[i * 4 + 2], dot);
        dot = fmaf(vv.w, qv[i * 4 + 3], dot);
      }
    }
    dot = wsum(dot) * 0.03125f;
    const float mn = fmaxf(m, dot);
    const float f = __expf(m - mn);
    const float p = __expf(dot - mn);
    lsum = lsum * f + p;
#pragma unroll
    for (int i = 0; i < 16; ++i) acc[i] = acc[i] * f + p * cv[i];
    m = mn;
  }

  if (extra != nullptr && w == 0) {
    const float* ep = extra + (size_t)b * D;
    float cv[16];
    float dot = 0.f;
    if (CBF) {
#pragma unroll
      for (int i = 0; i < 2; ++i)
#pragma unroll
        for (int j = 0; j < 8; ++j) {
          const float c = ep[(l + i * 64) * 8 + j];
          cv[i * 8 + j] = c;
          dot = fmaf(c, qv[i * 8 + j], dot);
        }
    } else {
#pragma unroll
      for (int i = 0; i < 4; ++i)
#pragma unroll
        for (int j = 0; j < 4; ++j) {
          const float c = ep[(l + i * 64) * 4 + j];
          cv[i * 4 + j] = c;
          dot = fmaf(c, qv[i * 4 + j], dot);
        }
    }
    dot = wsum(dot) * 0.03125f;
    const float mn = fmaxf(m, dot);
    const float f = __expf(m - mn);
    const float p = __expf(dot - mn);
    lsum = lsum * f + p;
#pragma unroll
    for (int i = 0; i < 16; ++i) acc[i] = acc[i] * f + p * cv[i];
    m = mn;
  }

  if (CBF) {
#pragma unroll
    for (int i = 0; i < 2; ++i)
#pragma unroll
      for (int j = 0; j < 8; ++j) accs[w][(l + i * 64) * 8 + j] = acc[i * 8 + j];
  } else {
#pragma unroll
    for (int i = 0; i < 4; ++i)
#pragma unroll
      for (int j = 0; j < 4; ++j) accs[w][(l + i * 64) * 4 + j] = acc[i * 4 + j];
  }
  if (l == 0) { mws[w] = m; lws[w] = lsum; }
  __syncthreads();

  const float M2 = fmaxf(fmaxf(mws[0], mws[1]), fmaxf(mws[2], mws[3]));
  const float c0 = __expf(mws[0] - M2), c1 = __expf(mws[1] - M2);
  const float c2 = __expf(mws[2] - M2), c3 = __expf(mws[3] - M2);
  const float inv = 1.f / (lws[0] * c0 + lws[1] * c1 + lws[2] * c2 + lws[3] * c3);
  ushort4 ob;
  float o0 = (accs[0][tid * 4 + 0] * c0 + accs[1][tid * 4 + 0] * c1 +
              accs[2][tid * 4 + 0] * c2 + accs[3][tid * 4 + 0] * c3) * inv;
  float o1 = (accs[0][tid * 4 + 1] * c0 + accs[1][tid * 4 + 1] * c1 +
              accs[2][tid * 4 + 1] * c2 + accs[3][tid * 4 + 1] * c3) * inv;
  float o2 = (accs[0][tid * 4 + 2] * c0 + accs[1][tid * 4 + 2] * c1 +
              accs[2][tid * 4 + 2] * c2 + accs[3][tid * 4 + 2] * c3) * inv;
  float o3 = (accs[0][tid * 4 + 3] * c0 + accs[1][tid * 4 + 3] * c1 +
              accs[2][tid * 4 + 3] * c2 + accs[3][tid * 4 + 3] * c3) * inv;
  ob.x = f2bf(o0); ob.y = f2bf(o1); ob.z = f2bf(o2); ob.w = f2bf(o3);
  ((ushort4*)(ctxb + (size_t)b * D))[tid] = ob;
}

// ---------------- LayerNorm (bf16 out) ----------------
__global__ __launch_bounds__(256) void ln_kernel(
    const float* __restrict__ x, const float* __restrict__ g,
    const float* __restrict__ bb, ushort* __restrict__ out) {
  const int b = blockIdx.x;
  const int tid = threadIdx.x;
  const int wave = tid >> 6, lane = tid & 63;
  const float4 xv = ((const float4*)(x + (int64_t)b * D))[tid];
  float s = (xv.x + xv.y) + (xv.z + xv.w);
  float ss = fmaf(xv.x, xv.x, fmaf(xv.y, xv.y, fmaf(xv.z, xv.z, xv.w * xv.w)));
  s = wsum(s);
  ss = wsum(ss);
  __shared__ float as_[4], bs_[4];
  if (lane == 0) { as_[wave] = s; bs_[wave] = ss; }
  __syncthreads();
  const float tot = (as_[0] + as_[1]) + (as_[2] + as_[3]);
  const float tots = (bs_[0] + bs_[1]) + (bs_[2] + bs_[3]);
  const float mu = tot * (1.f / 1024.f);
  const float var = tots * (1.f / 1024.f) - mu * mu;
  const float rs = rsqrtf(var + 1e-5f);
  const float4 gv = ((const float4*)g)[tid];
  const float4 bv = ((const float4*)bb)[tid];
  ushort4 o;
  o.x = f2bf((xv.x - mu) * rs * gv.x + bv.x);
  o.y = f2bf((xv.y - mu) * rs * gv.y + bv.y);
  o.z = f2bf((xv.z - mu) * rs * gv.z + bv.z);
  o.w = f2bf((xv.w - mu) * rs * gv.w + bv.w);
  ((ushort4*)(out + (int64_t)b * D))[tid] = o;
}

// ---------------- launch ----------------
extern "C" void kernel_launch(void* const* d_in, const int* in_sizes, int n_in,
                              void* d_out, int out_size, void* d_ws, size_t ws_size,
                              hipStream_t stream) {
  const float* x = (const float*)d_in[0];
  const float* conv = (const float*)d_in[1];
  const float* dst = (const float*)d_in[2];
  const float* Wdk = (const float*)d_in[3];
  const float* Wk = (const float*)d_in[4];
  const float* eW1 = (const float*)d_in[5];
  const float* eb1 = (const float*)d_in[6];
  const float* eW2 = (const float*)d_in[7];
  const float* eb2 = (const float*)d_in[8];
  const float* dpW = (const float*)d_in[9];
  const float* dpb = (const float*)d_in[10];
  const float* opW = (const float*)d_in[11];
  const float* opb = (const float*)d_in[12];
  const float* lng = (const float*)d_in[13];
  const float* lnb = (const float*)d_in[14];
  const float* mW1 = (const float*)d_in[15];
  const float* mb1 = (const float*)d_in[16];
  const float* mW2 = (const float*)d_in[17];
  const float* mb2 = (const float*)d_in[18];

  float* xout = (float*)d_out;
  float* conv_out = xout + (int64_t)B * D;

  const size_t MB = 1u << 20;
  char* p = (char*)d_ws;
  ushort* Wkt  = (ushort*)(p);              // 2 MB
  ushort* eW1t = (ushort*)(p + 2 * MB);     // 8 MB
  ushort* eW2t = (ushort*)(p + 10 * MB);    // 8 MB
  ushort* mW1t = (ushort*)(p + 18 * MB);    // 8 MB
  ushort* mW2t = (ushort*)(p + 26 * MB);    // 8 MB
  ushort* dpWb = (ushort*)(p + 34 * MB);    // 2 MB
  ushort* opWb = (ushort*)(p + 36 * MB);    // 2 MB
  ushort* xb   = (ushort*)(p + 38 * MB);    // 2 MB
  float* xkbuf = (float*)(p + 40 * MB);     // 4 MB
  float* extra = (float*)(p + 44 * MB);     // 4 MB
  ushort* rbuf = (ushort*)(p + 48 * MB);    // 0.5 -> pad 1 MB
  ushort* ctxb = (ushort*)(p + 49 * MB);    // 2 MB
  ushort* h1b  = (ushort*)(p + 51 * MB);    // 8 MB
  float* qbuf  = (float*)(p + 59 * MB);     // 4 MB
  float* x1    = (float*)(p + 63 * MB);     // 4 MB
  ushort* hlnb = (ushort*)(p + 67 * MB);    // 2 MB
  float* part  = (float*)(p + 69 * MB);     // 16 MB
  ushort* cbf  = (ushort*)(p + 85 * MB);    // 128 MB
  const bool use_cbf = ws_size >= 214 * MB;

  const dim3 blk(256);

  // weight converts / transposes
  transpose_bf16_kernel<<<dim3(32, 32), blk, 0, stream>>>(Wk, Wkt, 1024, 1024);
  transpose_bf16_kernel<<<dim3(128, 32), blk, 0, stream>>>(eW1, eW1t, 1024, 4096);
  transpose_bf16_kernel<<<dim3(32, 128), blk, 0, stream>>>(eW2, eW2t, 4096, 1024);
  transpose_bf16_kernel<<<dim3(128, 32), blk, 0, stream>>>(mW1, mW1t, 1024, 4096);
  transpose_bf16_kernel<<<dim3(32, 128), blk, 0, stream>>>(mW2, mW2t, 4096, 1024);
  cvt_bf16_kernel<<<dim3(1024), blk, 0, stream>>>(dpW, dpWb, 262144);
  cvt_bf16_kernel<<<dim3(1024), blk, 0, stream>>>(opW, opWb, 262144);
  cvt_bf16_kernel<<<dim3(1024), blk, 0, stream>>>(x, xb, 262144);

  // xk = x @ Wk  (split-K 4)
  gemm_mfma<true, false, false><<<dim3(8, 8, 4), blk, 0, stream>>>(
      xb, 1024, Wkt, 1024, nullptr, part, 1024, 256);
  reduce4_kernel<<<dim3(1024), blk, 0, stream>>>(part, nullptr, nullptr, xkbuf);

  // write step
  write_step_kernel<<<dim3(B), blk, 0, stream>>>(x, xkbuf, conv, conv_out,
                                                 use_cbf ? cbf : nullptr);
  // domain reads + dp projection
  domain_read_kernel<<<dim3(ND * B), dim3(64), 0, stream>>>(x, Wdk, dst, rbuf);
  gemm_mfma<false, false, false><<<dim3(8, 8, 1), blk, 0, stream>>>(
      rbuf, 256, dpWb, 1024, dpb, extra, 1024, 256);

  // ERG steps
  for (int t = 0; t < NSTEPS; ++t) {
    const float* qsrc = (t == 0) ? x : qbuf;
    if (use_cbf)
      attn2_kernel<true><<<dim3(B), blk, 0, stream>>>(qsrc, cbf, extra, ctxb);
    else
      attn2_kernel<false><<<dim3(B), blk, 0, stream>>>(qsrc, conv_out, extra, ctxb);
    gemm_mfma<false, true, true><<<dim3(32, 8, 1), blk, 0, stream>>>(
        ctxb, 1024, eW1t, 1024, eb1, h1b, 4096, 1024);
    gemm_mfma<true, false, false><<<dim3(8, 8, 4), blk, 0, stream>>>(
        h1b, 4096, eW2t, 4096, nullptr, part, 1024, 1024);
    reduce4_kernel<<<dim3(1024), blk, 0, stream>>>(part, eb2, qsrc, qbuf);
  }

  // read attention + out_proj
  if (use_cbf)
    attn2_kernel<true><<<dim3(B), blk, 0, stream>>>(qbuf, cbf, nullptr, ctxb);
  else
    attn2_kernel<false><<<dim3(B), blk, 0, stream>>>(qbuf, conv_out, nullptr, ctxb);
  gemm_mfma<true, false, false><<<dim3(8, 8, 4), blk, 0, stream>>>(
      ctxb, 1024, opWb, 1024, nullptr, part, 1024, 256);
  reduce4_kernel<<<dim3(1024), blk, 0, stream>>>(part, opb, x, x1);

  // LN + MLP
  ln_kernel<<<dim3(B), blk, 0, stream>>>(x1, lng, lnb, hlnb);
  gemm_mfma<false, true, true><<<dim3(32, 8, 1), blk, 0, stream>>>(
      hlnb, 1024, mW1t, 1024, mb1, h1b, 4096, 1024);
  gemm_mfma<true, false, false><<<dim3(8, 8, 4), blk, 0, stream>>>(
      h1b, 4096, mW2t, 4096, nullptr, part, 1024, 1024);
  reduce4_kernel<<<dim3(1024), blk, 0, stream>>>(part, mb2, x1, xout);
}